// Round 6
// baseline (308.167 us; speedup 1.0000x reference)
//
#include <hip/hip_runtime.h>

#define T_TRIG 48
#define S_SPAN 128
#define NN (T_TRIG * S_SPAN)      // 6144 nodes
#define D 128                     // feature dim
#define GRID 384                  // 384 blocks x 256 thr; guaranteed co-resident at 2 blk/CU

typedef __attribute__((ext_vector_type(8))) short sh8;
typedef __attribute__((ext_vector_type(4))) float f32x4;
typedef __attribute__((ext_vector_type(4))) unsigned short us4;

__device__ inline unsigned short f2bf(float v) {
    unsigned u = __float_as_uint(v);
    unsigned r = u + 0x7FFFu + ((u >> 16) & 1u);   // RTNE
    return (unsigned short)(r >> 16);
}
__device__ inline float bf2f(unsigned short b) {
    return __uint_as_float(((unsigned)b) << 16);
}

struct Params {
    const float *pe, *W1, *as1, *ad1, *b1, *W2, *as2, *ad2, *b2;
    float* out;
    unsigned int* bar;
    unsigned short *x2h, *x2l, *w2h, *w2l;
    float *H, *numr, *asrc, *adst, *den;
};

// ---- software grid barrier: monotone counter, device-scope atomics --------
__device__ inline void gridbar(unsigned int* bar, unsigned int target) {
    __syncthreads();
    if (threadIdx.x == 0) {
        __threadfence();                       // release: wbl2 so other XCDs see our writes
        atomicAdd(bar, 1u);
        while (atomicAdd(bar, 0u) < target)    // atomic load (device scope)
            __builtin_amdgcn_s_sleep(1);
        __threadfence();                       // acquire: invalidate caches
    }
    __syncthreads();
}

// ---- common GEMM epilogue: store H tile + attention scalars ---------------
__device__ inline void store_epi(float* H, float* asrc, float* adst,
                                 const float* att_s, const float* att_d,
                                 const f32x4& a0, const f32x4& a1,
                                 int row0, int hp, int c, int kg)
{
    #pragma unroll
    for (int i = 0; i < 4; ++i) {
        H[(size_t)(row0 + kg * 4 + i) * D + hp * 32 + c]      = a0[i];
        H[(size_t)(row0 + kg * 4 + i) * D + hp * 32 + 16 + c] = a1[i];
    }
    const float as0 = att_s[hp * 32 + c],  as1v = att_s[hp * 32 + 16 + c];
    const float ad0 = att_d[hp * 32 + c],  ad1v = att_d[hp * 32 + 16 + c];
    #pragma unroll
    for (int i = 0; i < 4; ++i) {
        float ps = a0[i] * as0 + a1[i] * as1v;
        float pd = a0[i] * ad0 + a1[i] * ad1v;
        ps += __shfl_xor(ps, 1); pd += __shfl_xor(pd, 1);
        ps += __shfl_xor(ps, 2); pd += __shfl_xor(pd, 2);
        ps += __shfl_xor(ps, 4); pd += __shfl_xor(pd, 4);
        ps += __shfl_xor(ps, 8); pd += __shfl_xor(pd, 8);
        if (c == 0) {
            int rr = row0 + kg * 4 + i;
            asrc[rr * 4 + hp] = ps;
            adst[rr * 4 + hp] = pd;
        }
    }
}

// ---- phase 1: layer-1 GEMM from fp32 inputs (in-register split-bf16);
//      tail blocks also pack W2 into fragment layout ------------------------
__device__ void gemm_l1(const Params& p, int b, int t)
{
    const int w = t >> 6, l = t & 63;
    const int c = l & 15, kg = l >> 4;
    const int row0 = b * 16;
    const int nt0 = w * 2, nt1 = nt0 + 1;

    f32x4 a0 = {0,0,0,0}, a1 = {0,0,0,0};
    #pragma unroll
    for (int kc = 0; kc < 4; ++kc) {
        const float* xp = p.pe + (size_t)(row0 + c) * D + kc * 32 + kg * 8;
        float4 x0 = *(const float4*)xp;
        float4 x1 = *(const float4*)(xp + 4);
        float xs[8] = {x0.x, x0.y, x0.z, x0.w, x1.x, x1.y, x1.z, x1.w};
        sh8 ah, al;
        #pragma unroll
        for (int i = 0; i < 8; ++i) {
            unsigned short h = f2bf(xs[i]);
            ah[i] = (short)h;
            al[i] = (short)f2bf(xs[i] - bf2f(h));
        }
        const int kb = kc * 32 + kg * 8;
        sh8 b0h, b0l, b1h, b1l;
        #pragma unroll
        for (int i = 0; i < 8; ++i) {
            float v0 = p.W1[(size_t)(kb + i) * D + nt0 * 16 + c];
            float v1 = p.W1[(size_t)(kb + i) * D + nt1 * 16 + c];
            unsigned short h0 = f2bf(v0);
            b0h[i] = (short)h0; b0l[i] = (short)f2bf(v0 - bf2f(h0));
            unsigned short h1 = f2bf(v1);
            b1h[i] = (short)h1; b1l[i] = (short)f2bf(v1 - bf2f(h1));
        }
        a0 = __builtin_amdgcn_mfma_f32_16x16x32_bf16(ah, b0h, a0, 0, 0, 0);
        a0 = __builtin_amdgcn_mfma_f32_16x16x32_bf16(al, b0h, a0, 0, 0, 0);
        a0 = __builtin_amdgcn_mfma_f32_16x16x32_bf16(ah, b0l, a0, 0, 0, 0);
        a1 = __builtin_amdgcn_mfma_f32_16x16x32_bf16(ah, b1h, a1, 0, 0, 0);
        a1 = __builtin_amdgcn_mfma_f32_16x16x32_bf16(al, b1h, a1, 0, 0, 0);
        a1 = __builtin_amdgcn_mfma_f32_16x16x32_bf16(ah, b1l, a1, 0, 0, 0);
    }
    store_epi(p.H, p.asrc, p.adst, p.as1, p.ad1, a0, a1, row0, w, c, kg);

    if (b >= GRID - 8) {                       // pack W2 frags (8 blocks)
        const int nt = b - (GRID - 8);
        const int kc = t >> 6;
        const int ll = t & 63;
        const int n = nt * 16 + (ll & 15);
        const int kb = kc * 32 + (ll >> 4) * 8;
        unsigned short hb[8], lb[8];
        #pragma unroll
        for (int i = 0; i < 8; ++i) {
            float v = p.W2[(size_t)(kb + i) * D + n];
            unsigned short h = f2bf(v);
            hb[i] = h;
            lb[i] = f2bf(v - bf2f(h));
        }
        size_t base = ((size_t)(nt * 4 + kc) * 64 + ll) * 8;
        #pragma unroll
        for (int i = 0; i < 8; ++i) { p.w2h[base + i] = hb[i]; p.w2l[base + i] = lb[i]; }
    }
}

// ---- phase 4: layer-2 GEMM from pre-split bf16 ----------------------------
__device__ void gemm_l2(const Params& p, int b, int t)
{
    const int w = t >> 6, l = t & 63;
    const int c = l & 15, kg = l >> 4;
    const int row0 = b * 16;
    const int nt0 = w * 2, nt1 = nt0 + 1;

    const sh8* Xh8 = (const sh8*)p.x2h;
    const sh8* Xl8 = (const sh8*)p.x2l;
    const sh8* Wh8 = (const sh8*)p.w2h;
    const sh8* Wl8 = (const sh8*)p.w2l;

    f32x4 a0 = {0,0,0,0}, a1 = {0,0,0,0};
    #pragma unroll
    for (int kc = 0; kc < 4; ++kc) {
        const int xi = (row0 + c) * 16 + kc * 4 + kg;
        sh8 ah = Xh8[xi];
        sh8 al = Xl8[xi];
        sh8 b0h = Wh8[(nt0 * 4 + kc) * 64 + l];
        sh8 b0l = Wl8[(nt0 * 4 + kc) * 64 + l];
        sh8 b1h = Wh8[(nt1 * 4 + kc) * 64 + l];
        sh8 b1l = Wl8[(nt1 * 4 + kc) * 64 + l];
        a0 = __builtin_amdgcn_mfma_f32_16x16x32_bf16(ah, b0h, a0, 0, 0, 0);
        a0 = __builtin_amdgcn_mfma_f32_16x16x32_bf16(al, b0h, a0, 0, 0, 0);
        a0 = __builtin_amdgcn_mfma_f32_16x16x32_bf16(ah, b0l, a0, 0, 0, 0);
        a1 = __builtin_amdgcn_mfma_f32_16x16x32_bf16(ah, b1h, a1, 0, 0, 0);
        a1 = __builtin_amdgcn_mfma_f32_16x16x32_bf16(al, b1h, a1, 0, 0, 0);
        a1 = __builtin_amdgcn_mfma_f32_16x16x32_bf16(ah, b1l, a1, 0, 0, 0);
    }
    store_epi(p.H, p.asrc, p.adst, p.as2, p.ad2, a0, a1, row0, w, c, kg);
}

// ---- row aggregation: block = (r, h, half) = 48*4*2 = 384 -----------------
__device__ void do_row(const float* H, const float* asrc, const float* adst,
                       float* numr, float* den, float* sm, int b, int t)
{
    float (*sh_h)[32] = (float(*)[32])sm;          // 128 x 32
    float* sh_as = sm + 128 * 32;                  // 128
    const int r = b >> 3, sub = b & 7;
    const int h = sub >> 1, half = sub & 1;
    const int base = r * S_SPAN;

    #pragma unroll
    for (int it = 0; it < 4; ++it) {
        int chunk = t + it * 256;
        int cp = chunk >> 3, fc = chunk & 7;
        *(float4*)&sh_h[cp][fc * 4] =
            *(const float4*)&H[(size_t)(base + cp) * D + h * 32 + fc * 4];
    }
    if (t < 128) sh_as[t] = asrc[(base + t) * 4 + h];
    __syncthreads();

    const int fg = t & 3;
    const int cc = half * 64 + (t >> 2);
    const float ad = adst[(base + cc) * 4 + h];
    float4 n0 = {0,0,0,0}, n1 = {0,0,0,0};
    float dn = 0.f;

    #pragma unroll 4
    for (int cp = 0; cp < S_SPAN; ++cp) {
        float e = sh_as[cp] + ad;
        e = fmaxf(e, 0.2f * e);
        float wgt = __expf(e);
        dn += wgt;
        float4 h0 = *(float4*)&sh_h[cp][fg * 8];
        float4 h1 = *(float4*)&sh_h[cp][fg * 8 + 4];
        n0.x = fmaf(wgt, h0.x, n0.x); n0.y = fmaf(wgt, h0.y, n0.y);
        n0.z = fmaf(wgt, h0.z, n0.z); n0.w = fmaf(wgt, h0.w, n0.w);
        n1.x = fmaf(wgt, h1.x, n1.x); n1.y = fmaf(wgt, h1.y, n1.y);
        n1.z = fmaf(wgt, h1.z, n1.z); n1.w = fmaf(wgt, h1.w, n1.w);
    }

    const int n = base + cc;
    *(float4*)&numr[(size_t)n * D + h * 32 + fg * 8]     = n0;
    *(float4*)&numr[(size_t)n * D + h * 32 + fg * 8 + 4] = n1;
    if (fg == 0) den[n * 4 + h] = dn;
    __syncthreads();                               // LDS reused next phase
}

// ---- col aggregation + finalize: block = (third, c) = 3*128 = 384 ---------
__device__ void do_col(const float* H, const float* asrc, const float* adst,
                       const float* numr, const float* den, const float* bias,
                       float* outf, unsigned short* xh, unsigned short* xl,
                       float* sm, int b, int t)
{
    float (*sh_h)[D] = (float(*)[D])sm;                      // 48 x 128
    float (*sh_as)[T_TRIG] = (float(*)[T_TRIG])(sm + T_TRIG * D);
    const int c = b & 127, third = b >> 7;

    #pragma unroll
    for (int it = 0; it < 6; ++it) {
        int chunk = t + it * 256;
        int tt = chunk >> 5, fc = chunk & 31;
        *(float4*)&sh_h[tt][fc * 4] =
            *(const float4*)&H[(size_t)(tt * S_SPAN + c) * D + fc * 4];
    }
    if (t < 4 * T_TRIG) {
        int hh = t / T_TRIG, tt = t - hh * T_TRIG;
        sh_as[hh][tt] = asrc[(tt * S_SPAN + c) * 4 + hh];
    }
    __syncthreads();

    const int f4g = t & 31, tg = t >> 5, head = f4g >> 3;
    const int t0 = third * 16 + tg * 2;
    float4 num[2] = {{0,0,0,0},{0,0,0,0}};
    float dn[2] = {0.f, 0.f};
    float ad[2] = { adst[(t0 * S_SPAN + c) * 4 + head],
                    adst[((t0 + 1) * S_SPAN + c) * 4 + head] };

    for (int tp = 0; tp < T_TRIG; ++tp) {
        float a = sh_as[head][tp];
        float4 hv = *(float4*)&sh_h[tp][f4g * 4];
        #pragma unroll
        for (int dd = 0; dd < 2; ++dd) {
            float e = a + ad[dd];
            e = fmaxf(e, 0.2f * e);
            float w = __expf(e);
            w = (tp == t0 + dd) ? 0.f : w;      // exclude own row
            dn[dd] += w;
            num[dd].x = fmaf(w, hv.x, num[dd].x);
            num[dd].y = fmaf(w, hv.y, num[dd].y);
            num[dd].z = fmaf(w, hv.z, num[dd].z);
            num[dd].w = fmaf(w, hv.w, num[dd].w);
        }
    }

    const float4 b4 = *(const float4*)&bias[f4g * 4];
    #pragma unroll
    for (int dd = 0; dd < 2; ++dd) {
        const int n = (t0 + dd) * S_SPAN + c;
        float4 nr = *(const float4*)&numr[(size_t)n * D + f4g * 4];
        float inv = 1.f / (den[n * 4 + head] + dn[dd]);
        float o[4];
        o[0] = (nr.x + num[dd].x) * inv + b4.x;
        o[1] = (nr.y + num[dd].y) * inv + b4.y;
        o[2] = (nr.z + num[dd].z) * inv + b4.z;
        o[3] = (nr.w + num[dd].w) * inv + b4.w;
        #pragma unroll
        for (int q = 0; q < 4; ++q)
            o[q] = o[q] > 0.f ? o[q] : (__expf(o[q]) - 1.f);
        if (xh) {
            us4 hv4, lv4;
            #pragma unroll
            for (int q = 0; q < 4; ++q) {
                unsigned short hq = f2bf(o[q]);
                hv4[q] = hq;
                lv4[q] = f2bf(o[q] - bf2f(hq));
            }
            *(us4*)&xh[(size_t)n * D + f4g * 4] = hv4;
            *(us4*)&xl[(size_t)n * D + f4g * 4] = lv4;
        } else {
            float4 o4 = {o[0], o[1], o[2], o[3]};
            *(float4*)&outf[(size_t)n * D + f4g * 4] = o4;
        }
    }
    __syncthreads();                               // LDS reused next phase
}

// ---- the single fused kernel ----------------------------------------------
__global__ __launch_bounds__(256, 2) void fused_gat_kernel(Params p)
{
    __shared__ float sm[T_TRIG * D + 4 * T_TRIG];   // 25,344 B (col phase max)
    const int b = blockIdx.x, t = threadIdx.x;

    gemm_l1(p, b, t);
    gridbar(p.bar, 1 * GRID);
    do_row(p.H, p.asrc, p.adst, p.numr, p.den, sm, b, t);
    gridbar(p.bar, 2 * GRID);
    do_col(p.H, p.asrc, p.adst, p.numr, p.den, p.b1, nullptr, p.x2h, p.x2l, sm, b, t);
    gridbar(p.bar, 3 * GRID);
    gemm_l2(p, b, t);
    gridbar(p.bar, 4 * GRID);
    do_row(p.H, p.asrc, p.adst, p.numr, p.den, sm, b, t);
    gridbar(p.bar, 5 * GRID);
    do_col(p.H, p.asrc, p.adst, p.numr, p.den, p.b2, p.out, nullptr, nullptr, sm, b, t);
}

// ---------------------------------------------------------------------------
extern "C" void kernel_launch(void* const* d_in, const int* in_sizes, int n_in,
                              void* d_out, int out_size, void* d_ws, size_t ws_size,
                              hipStream_t stream)
{
    Params p;
    p.pe  = (const float*)d_in[0];
    p.W1  = (const float*)d_in[1];
    p.as1 = (const float*)d_in[2];
    p.ad1 = (const float*)d_in[3];
    p.b1  = (const float*)d_in[4];
    p.W2  = (const float*)d_in[5];
    p.as2 = (const float*)d_in[6];
    p.ad2 = (const float*)d_in[7];
    p.b2  = (const float*)d_in[8];
    p.out = (float*)d_out;

    char* ws = (char*)d_ws;
    size_t off = 0;
    auto alloc = [&](size_t bytes) { char* r = ws + off; off += (bytes + 255) & ~255ull; return r; };
    p.bar  = (unsigned int*)alloc(256);
    p.x2h  = (unsigned short*)alloc((size_t)NN * D * 2);
    p.x2l  = (unsigned short*)alloc((size_t)NN * D * 2);
    p.w2h  = (unsigned short*)alloc((size_t)D * D * 2);
    p.w2l  = (unsigned short*)alloc((size_t)D * D * 2);
    p.H    = (float*)alloc((size_t)NN * D * 4);
    p.numr = (float*)alloc((size_t)NN * D * 4);
    p.asrc = (float*)alloc((size_t)NN * 4 * 4);
    p.adst = (float*)alloc((size_t)NN * 4 * 4);
    p.den  = (float*)alloc((size_t)NN * 4 * 4);

    hipMemsetAsync(p.bar, 0, 256, stream);
    fused_gat_kernel<<<dim3(GRID), dim3(256), 0, stream>>>(p);
}

// Round 8
// 248.097 us; speedup vs baseline: 1.2421x; 1.2421x over previous
//
#include <hip/hip_runtime.h>

#define T_TRIG 48
#define S_SPAN 128
#define NN (T_TRIG * S_SPAN)      // 6144 nodes
#define D 128                     // feature dim
#define GRID 384                  // co-resident at 2 blk/CU (512 >= 384)

typedef __attribute__((ext_vector_type(8))) short sh8;
typedef __attribute__((ext_vector_type(4))) float f32x4;
typedef __attribute__((ext_vector_type(4))) unsigned short us4;

__device__ inline unsigned short f2bf(float v) {
    unsigned u = __float_as_uint(v);
    unsigned r = u + 0x7FFFu + ((u >> 16) & 1u);   // RTNE
    return (unsigned short)(r >> 16);
}
__device__ inline float bf2f(unsigned short b) {
    return __uint_as_float(((unsigned)b) << 16);
}

struct Params {
    const float *pe, *W1, *as1, *ad1, *b1, *W2, *as2, *ad2, *b2;
    float* out;
    unsigned int* bar;
    unsigned short *x2h, *x2l, *w2h, *w2l;
    float *H, *numr, *asrc, *adst, *den;
};

// ---- software grid barrier --------------------------------------------------
// Release half: syncthreads (compiler drains vmcnt before s_barrier) + one
// buffer_wbl2 per block (flushes this XCD's dirty L2 lines to MALL/coherence
// point; cheap when little is dirty). Arrive via device-scope RMW.
// Spin via relaxed agent atomic LOAD (no RMW serialization; proven to observe
// remote RMWs in round 7). Acquire half: buffer_inv (drop stale clean lines;
// no writeback traffic) then syncthreads.
__device__ inline void gridbar(unsigned int* bar, unsigned int target) {
    asm volatile("s_waitcnt vmcnt(0)" ::: "memory");
    __syncthreads();
    if (threadIdx.x == 0) {
        asm volatile("buffer_wbl2 sc1\n\ts_waitcnt vmcnt(0)" ::: "memory");
        atomicAdd(bar, 1u);
        while (__hip_atomic_load(bar, __ATOMIC_RELAXED, __HIP_MEMORY_SCOPE_AGENT) < target)
            __builtin_amdgcn_s_sleep(4);
        asm volatile("buffer_inv sc1\n\ts_waitcnt vmcnt(0)" ::: "memory");
    }
    __syncthreads();
    __builtin_amdgcn_sched_barrier(0);
}

// ---- common GEMM epilogue: store H tile + attention scalars ---------------
__device__ inline void store_epi(float* H, float* asrc, float* adst,
                                 const float* att_s, const float* att_d,
                                 const f32x4& a0, const f32x4& a1,
                                 int row0, int hp, int c, int kg)
{
    #pragma unroll
    for (int i = 0; i < 4; ++i) {
        H[(size_t)(row0 + kg * 4 + i) * D + hp * 32 + c]      = a0[i];
        H[(size_t)(row0 + kg * 4 + i) * D + hp * 32 + 16 + c] = a1[i];
    }
    const float as0 = att_s[hp * 32 + c],  as1v = att_s[hp * 32 + 16 + c];
    const float ad0 = att_d[hp * 32 + c],  ad1v = att_d[hp * 32 + 16 + c];
    #pragma unroll
    for (int i = 0; i < 4; ++i) {
        float ps = a0[i] * as0 + a1[i] * as1v;
        float pd = a0[i] * ad0 + a1[i] * ad1v;
        ps += __shfl_xor(ps, 1); pd += __shfl_xor(pd, 1);
        ps += __shfl_xor(ps, 2); pd += __shfl_xor(pd, 2);
        ps += __shfl_xor(ps, 4); pd += __shfl_xor(pd, 4);
        ps += __shfl_xor(ps, 8); pd += __shfl_xor(pd, 8);
        if (c == 0) {
            int rr = row0 + kg * 4 + i;
            asrc[rr * 4 + hp] = ps;
            adst[rr * 4 + hp] = pd;
        }
    }
}

// ---- phase 1: layer-1 GEMM from fp32 inputs (in-register split-bf16);
//      tail blocks also pack W2 into fragment layout ------------------------
__device__ void gemm_l1(const Params& p, int b, int t)
{
    const int w = t >> 6, l = t & 63;
    const int c = l & 15, kg = l >> 4;
    const int row0 = b * 16;
    const int nt0 = w * 2, nt1 = nt0 + 1;

    f32x4 a0 = {0,0,0,0}, a1 = {0,0,0,0};
    #pragma unroll
    for (int kc = 0; kc < 4; ++kc) {
        const float* xp = p.pe + (size_t)(row0 + c) * D + kc * 32 + kg * 8;
        float4 x0 = *(const float4*)xp;
        float4 x1 = *(const float4*)(xp + 4);
        float xs[8] = {x0.x, x0.y, x0.z, x0.w, x1.x, x1.y, x1.z, x1.w};
        sh8 ah, al;
        #pragma unroll
        for (int i = 0; i < 8; ++i) {
            unsigned short h = f2bf(xs[i]);
            ah[i] = (short)h;
            al[i] = (short)f2bf(xs[i] - bf2f(h));
        }
        const int kb = kc * 32 + kg * 8;
        sh8 b0h, b0l, b1h, b1l;
        #pragma unroll
        for (int i = 0; i < 8; ++i) {
            float v0 = p.W1[(size_t)(kb + i) * D + nt0 * 16 + c];
            float v1 = p.W1[(size_t)(kb + i) * D + nt1 * 16 + c];
            unsigned short h0 = f2bf(v0);
            b0h[i] = (short)h0; b0l[i] = (short)f2bf(v0 - bf2f(h0));
            unsigned short h1 = f2bf(v1);
            b1h[i] = (short)h1; b1l[i] = (short)f2bf(v1 - bf2f(h1));
        }
        a0 = __builtin_amdgcn_mfma_f32_16x16x32_bf16(ah, b0h, a0, 0, 0, 0);
        a0 = __builtin_amdgcn_mfma_f32_16x16x32_bf16(al, b0h, a0, 0, 0, 0);
        a0 = __builtin_amdgcn_mfma_f32_16x16x32_bf16(ah, b0l, a0, 0, 0, 0);
        a1 = __builtin_amdgcn_mfma_f32_16x16x32_bf16(ah, b1h, a1, 0, 0, 0);
        a1 = __builtin_amdgcn_mfma_f32_16x16x32_bf16(al, b1h, a1, 0, 0, 0);
        a1 = __builtin_amdgcn_mfma_f32_16x16x32_bf16(ah, b1l, a1, 0, 0, 0);
    }
    store_epi(p.H, p.asrc, p.adst, p.as1, p.ad1, a0, a1, row0, w, c, kg);

    if (b >= GRID - 8) {                       // pack W2 frags (8 blocks)
        const int nt = b - (GRID - 8);
        const int kc = t >> 6;
        const int ll = t & 63;
        const int n = nt * 16 + (ll & 15);
        const int kb = kc * 32 + (ll >> 4) * 8;
        unsigned short hb[8], lb[8];
        #pragma unroll
        for (int i = 0; i < 8; ++i) {
            float v = p.W2[(size_t)(kb + i) * D + n];
            unsigned short h = f2bf(v);
            hb[i] = h;
            lb[i] = f2bf(v - bf2f(h));
        }
        size_t base = ((size_t)(nt * 4 + kc) * 64 + ll) * 8;
        #pragma unroll
        for (int i = 0; i < 8; ++i) { p.w2h[base + i] = hb[i]; p.w2l[base + i] = lb[i]; }
    }
}

// ---- phase 4: layer-2 GEMM from pre-split bf16 ----------------------------
__device__ void gemm_l2(const Params& p, int b, int t)
{
    const int w = t >> 6, l = t & 63;
    const int c = l & 15, kg = l >> 4;
    const int row0 = b * 16;
    const int nt0 = w * 2, nt1 = nt0 + 1;

    const sh8* Xh8 = (const sh8*)p.x2h;
    const sh8* Xl8 = (const sh8*)p.x2l;
    const sh8* Wh8 = (const sh8*)p.w2h;
    const sh8* Wl8 = (const sh8*)p.w2l;

    f32x4 a0 = {0,0,0,0}, a1 = {0,0,0,0};
    #pragma unroll
    for (int kc = 0; kc < 4; ++kc) {
        const int xi = (row0 + c) * 16 + kc * 4 + kg;
        sh8 ah = Xh8[xi];
        sh8 al = Xl8[xi];
        sh8 b0h = Wh8[(nt0 * 4 + kc) * 64 + l];
        sh8 b0l = Wl8[(nt0 * 4 + kc) * 64 + l];
        sh8 b1h = Wh8[(nt1 * 4 + kc) * 64 + l];
        sh8 b1l = Wl8[(nt1 * 4 + kc) * 64 + l];
        a0 = __builtin_amdgcn_mfma_f32_16x16x32_bf16(ah, b0h, a0, 0, 0, 0);
        a0 = __builtin_amdgcn_mfma_f32_16x16x32_bf16(al, b0h, a0, 0, 0, 0);
        a0 = __builtin_amdgcn_mfma_f32_16x16x32_bf16(ah, b0l, a0, 0, 0, 0);
        a1 = __builtin_amdgcn_mfma_f32_16x16x32_bf16(ah, b1h, a1, 0, 0, 0);
        a1 = __builtin_amdgcn_mfma_f32_16x16x32_bf16(al, b1h, a1, 0, 0, 0);
        a1 = __builtin_amdgcn_mfma_f32_16x16x32_bf16(ah, b1l, a1, 0, 0, 0);
    }
    store_epi(p.H, p.asrc, p.adst, p.as2, p.ad2, a0, a1, row0, w, c, kg);
}

// ---- row aggregation: block = (r, h, half) = 48*4*2 = 384 -----------------
__device__ void do_row(const float* H, const float* asrc, const float* adst,
                       float* numr, float* den, float* sm, int b, int t)
{
    float (*sh_h)[32] = (float(*)[32])sm;          // 128 x 32
    float* sh_as = sm + 128 * 32;                  // 128
    const int r = b >> 3, sub = b & 7;
    const int h = sub >> 1, half = sub & 1;
    const int base = r * S_SPAN;

    #pragma unroll
    for (int it = 0; it < 4; ++it) {
        int chunk = t + it * 256;
        int cp = chunk >> 3, fc = chunk & 7;
        *(float4*)&sh_h[cp][fc * 4] =
            *(const float4*)&H[(size_t)(base + cp) * D + h * 32 + fc * 4];
    }
    if (t < 128) sh_as[t] = asrc[(base + t) * 4 + h];
    __syncthreads();

    const int fg = t & 3;
    const int cc = half * 64 + (t >> 2);
    const float ad = adst[(base + cc) * 4 + h];
    float4 n0 = {0,0,0,0}, n1 = {0,0,0,0};
    float dn = 0.f;

    #pragma unroll 4
    for (int cp = 0; cp < S_SPAN; ++cp) {
        float e = sh_as[cp] + ad;
        e = fmaxf(e, 0.2f * e);
        float wgt = __expf(e);
        dn += wgt;
        float4 h0 = *(float4*)&sh_h[cp][fg * 8];
        float4 h1 = *(float4*)&sh_h[cp][fg * 8 + 4];
        n0.x = fmaf(wgt, h0.x, n0.x); n0.y = fmaf(wgt, h0.y, n0.y);
        n0.z = fmaf(wgt, h0.z, n0.z); n0.w = fmaf(wgt, h0.w, n0.w);
        n1.x = fmaf(wgt, h1.x, n1.x); n1.y = fmaf(wgt, h1.y, n1.y);
        n1.z = fmaf(wgt, h1.z, n1.z); n1.w = fmaf(wgt, h1.w, n1.w);
    }

    const int n = base + cc;
    *(float4*)&numr[(size_t)n * D + h * 32 + fg * 8]     = n0;
    *(float4*)&numr[(size_t)n * D + h * 32 + fg * 8 + 4] = n1;
    if (fg == 0) den[n * 4 + h] = dn;
    __syncthreads();                               // LDS reused next phase
}

// ---- col aggregation + finalize: block = (third, c) = 3*128 = 384 ---------
__device__ void do_col(const float* H, const float* asrc, const float* adst,
                       const float* numr, const float* den, const float* bias,
                       float* outf, unsigned short* xh, unsigned short* xl,
                       float* sm, int b, int t)
{
    float (*sh_h)[D] = (float(*)[D])sm;                      // 48 x 128
    float (*sh_as)[T_TRIG] = (float(*)[T_TRIG])(sm + T_TRIG * D);
    const int c = b & 127, third = b >> 7;

    #pragma unroll
    for (int it = 0; it < 6; ++it) {
        int chunk = t + it * 256;
        int tt = chunk >> 5, fc = chunk & 31;
        *(float4*)&sh_h[tt][fc * 4] =
            *(const float4*)&H[(size_t)(tt * S_SPAN + c) * D + fc * 4];
    }
    if (t < 4 * T_TRIG) {
        int hh = t / T_TRIG, tt = t - hh * T_TRIG;
        sh_as[hh][tt] = asrc[(tt * S_SPAN + c) * 4 + hh];
    }
    __syncthreads();

    const int f4g = t & 31, tg = t >> 5, head = f4g >> 3;
    const int t0 = third * 16 + tg * 2;
    float4 num[2] = {{0,0,0,0},{0,0,0,0}};
    float dn[2] = {0.f, 0.f};
    float ad[2] = { adst[(t0 * S_SPAN + c) * 4 + head],
                    adst[((t0 + 1) * S_SPAN + c) * 4 + head] };

    for (int tp = 0; tp < T_TRIG; ++tp) {
        float a = sh_as[head][tp];
        float4 hv = *(float4*)&sh_h[tp][f4g * 4];
        #pragma unroll
        for (int dd = 0; dd < 2; ++dd) {
            float e = a + ad[dd];
            e = fmaxf(e, 0.2f * e);
            float w = __expf(e);
            w = (tp == t0 + dd) ? 0.f : w;      // exclude own row
            dn[dd] += w;
            num[dd].x = fmaf(w, hv.x, num[dd].x);
            num[dd].y = fmaf(w, hv.y, num[dd].y);
            num[dd].z = fmaf(w, hv.z, num[dd].z);
            num[dd].w = fmaf(w, hv.w, num[dd].w);
        }
    }

    const float4 b4 = *(const float4*)&bias[f4g * 4];
    #pragma unroll
    for (int dd = 0; dd < 2; ++dd) {
        const int n = (t0 + dd) * S_SPAN + c;
        float4 nr = *(const float4*)&numr[(size_t)n * D + f4g * 4];
        float inv = 1.f / (den[n * 4 + head] + dn[dd]);
        float o[4];
        o[0] = (nr.x + num[dd].x) * inv + b4.x;
        o[1] = (nr.y + num[dd].y) * inv + b4.y;
        o[2] = (nr.z + num[dd].z) * inv + b4.z;
        o[3] = (nr.w + num[dd].w) * inv + b4.w;
        #pragma unroll
        for (int q = 0; q < 4; ++q)
            o[q] = o[q] > 0.f ? o[q] : (__expf(o[q]) - 1.f);
        if (xh) {
            us4 hv4, lv4;
            #pragma unroll
            for (int q = 0; q < 4; ++q) {
                unsigned short hq = f2bf(o[q]);
                hv4[q] = hq;
                lv4[q] = f2bf(o[q] - bf2f(hq));
            }
            *(us4*)&xh[(size_t)n * D + f4g * 4] = hv4;
            *(us4*)&xl[(size_t)n * D + f4g * 4] = lv4;
        } else {
            float4 o4 = {o[0], o[1], o[2], o[3]};
            *(float4*)&outf[(size_t)n * D + f4g * 4] = o4;
        }
    }
    __syncthreads();                               // LDS reused next phase
}

// ---- the single fused kernel ----------------------------------------------
__global__ __launch_bounds__(256, 2) void fused_gat_kernel(Params p)
{
    __shared__ float sm[T_TRIG * D + 4 * T_TRIG];   // 25,344 B (col phase max)
    const int b = blockIdx.x, t = threadIdx.x;

    gemm_l1(p, b, t);
    gridbar(p.bar, 1 * GRID);
    do_row(p.H, p.asrc, p.adst, p.numr, p.den, sm, b, t);
    gridbar(p.bar, 2 * GRID);
    do_col(p.H, p.asrc, p.adst, p.numr, p.den, p.b1, nullptr, p.x2h, p.x2l, sm, b, t);
    gridbar(p.bar, 3 * GRID);
    gemm_l2(p, b, t);
    gridbar(p.bar, 4 * GRID);
    do_row(p.H, p.asrc, p.adst, p.numr, p.den, sm, b, t);
    gridbar(p.bar, 5 * GRID);
    do_col(p.H, p.asrc, p.adst, p.numr, p.den, p.b2, p.out, nullptr, nullptr, sm, b, t);
}

// ---------------------------------------------------------------------------
extern "C" void kernel_launch(void* const* d_in, const int* in_sizes, int n_in,
                              void* d_out, int out_size, void* d_ws, size_t ws_size,
                              hipStream_t stream)
{
    Params p;
    p.pe  = (const float*)d_in[0];
    p.W1  = (const float*)d_in[1];
    p.as1 = (const float*)d_in[2];
    p.ad1 = (const float*)d_in[3];
    p.b1  = (const float*)d_in[4];
    p.W2  = (const float*)d_in[5];
    p.as2 = (const float*)d_in[6];
    p.ad2 = (const float*)d_in[7];
    p.b2  = (const float*)d_in[8];
    p.out = (float*)d_out;

    char* ws = (char*)d_ws;
    size_t off = 0;
    auto alloc = [&](size_t bytes) { char* r = ws + off; off += (bytes + 255) & ~255ull; return r; };
    p.bar  = (unsigned int*)alloc(256);
    p.x2h  = (unsigned short*)alloc((size_t)NN * D * 2);
    p.x2l  = (unsigned short*)alloc((size_t)NN * D * 2);
    p.w2h  = (unsigned short*)alloc((size_t)D * D * 2);
    p.w2l  = (unsigned short*)alloc((size_t)D * D * 2);
    p.H    = (float*)alloc((size_t)NN * D * 4);
    p.numr = (float*)alloc((size_t)NN * D * 4);
    p.asrc = (float*)alloc((size_t)NN * 4 * 4);
    p.adst = (float*)alloc((size_t)NN * 4 * 4);
    p.den  = (float*)alloc((size_t)NN * 4 * 4);

    hipMemsetAsync(p.bar, 0, 256, stream);
    fused_gat_kernel<<<dim3(GRID), dim3(256), 0, stream>>>(p);
}

// Round 9
// 95.959 us; speedup vs baseline: 3.2114x; 2.5854x over previous
//
#include <hip/hip_runtime.h>

#define T_TRIG 48
#define S_SPAN 128
#define NN (T_TRIG * S_SPAN)      // 6144 nodes
#define D 128                     // feature dim
#define GRID 192                  // (r,h) blocks; <= 256 CUs -> co-resident always
#define BLK 512

typedef __attribute__((ext_vector_type(8))) short sh8;
typedef __attribute__((ext_vector_type(4))) float f32x4;
typedef __attribute__((ext_vector_type(4))) unsigned short us4;

__device__ inline unsigned short f2bf(float v) {
    unsigned u = __float_as_uint(v);
    unsigned r = u + 0x7FFFu + ((u >> 16) & 1u);   // RTNE
    return (unsigned short)(r >> 16);
}
__device__ inline float bf2f(unsigned short b) {
    return __uint_as_float(((unsigned)b) << 16);
}

struct Params {
    const float *pe, *W1, *as1, *ad1, *b1, *W2, *as2, *ad2, *b2;
    float* out;
    unsigned int* bar;
    unsigned short *x2h, *x2l;
    float *H, *numr, *asrc, *adst, *den;
};

// ---- grid barrier (round-8-proven semantics, fewer/cheaper instances) -----
__device__ inline void gridbar(unsigned int* cnt) {
    asm volatile("s_waitcnt vmcnt(0)" ::: "memory");
    __syncthreads();
    if (threadIdx.x == 0) {
        asm volatile("buffer_wbl2 sc1\n\ts_waitcnt vmcnt(0)" ::: "memory");
        atomicAdd(cnt, 1u);
        while (__hip_atomic_load(cnt, __ATOMIC_RELAXED, __HIP_MEMORY_SCOPE_AGENT) < GRID)
            __builtin_amdgcn_s_sleep(8);
        asm volatile("buffer_inv sc1\n\ts_waitcnt vmcnt(0)" ::: "memory");
    }
    __syncthreads();
    __builtin_amdgcn_sched_barrier(0);
}

// ---------------------------------------------------------------------------
// GR phase: block (r,h). GEMM for grid-row r (128 nodes) x head h (32 feats),
// split-bf16 MFMA, H slice kept in LDS; then block-local row aggregation.
// Publishes H, asrc, adst, numr, den slices to global for the col phase.
// ---------------------------------------------------------------------------
template<int LAYER>
__device__ void gr_phase(const Params& p, float* sm, int b, int t)
{
    const int r = b >> 2, h = b & 3;
    const int w = t >> 6, l = t & 63;
    const int c = l & 15, kg = l >> 4;
    const int row0 = r * S_SPAN + w * 16;   // global node base for this wave
    const int col0 = h * 32;

    float (*sh_h)[36] = (float(*)[36])sm;          // 128 x 36 (padded)
    float* sh_as = sm + 128 * 36;
    float* sh_ad = sh_as + 128;

    const float* W     = (LAYER == 1) ? p.W1  : p.W2;
    const float* att_s = (LAYER == 1) ? p.as1 : p.as2;
    const float* att_d = (LAYER == 1) ? p.ad1 : p.ad2;

    f32x4 a0 = {0,0,0,0}, a1 = {0,0,0,0};
    #pragma unroll
    for (int kc = 0; kc < 4; ++kc) {
        sh8 ah, al;
        if (LAYER == 1) {
            const float* xp = p.pe + (size_t)(row0 + c) * D + kc * 32 + kg * 8;
            float4 x0 = *(const float4*)xp;
            float4 x1 = *(const float4*)(xp + 4);
            float xs[8] = {x0.x, x0.y, x0.z, x0.w, x1.x, x1.y, x1.z, x1.w};
            #pragma unroll
            for (int i = 0; i < 8; ++i) {
                unsigned short hh = f2bf(xs[i]);
                ah[i] = (short)hh;
                al[i] = (short)f2bf(xs[i] - bf2f(hh));
            }
        } else {
            const int xi = (row0 + c) * 16 + kc * 4 + kg;
            ah = ((const sh8*)p.x2h)[xi];
            al = ((const sh8*)p.x2l)[xi];
        }
        const int kb = kc * 32 + kg * 8;
        sh8 b0h, b0l, b1h, b1l;
        #pragma unroll
        for (int i = 0; i < 8; ++i) {
            float v0 = W[(size_t)(kb + i) * D + col0 + c];
            float v1 = W[(size_t)(kb + i) * D + col0 + 16 + c];
            unsigned short h0 = f2bf(v0);
            b0h[i] = (short)h0; b0l[i] = (short)f2bf(v0 - bf2f(h0));
            unsigned short h1 = f2bf(v1);
            b1h[i] = (short)h1; b1l[i] = (short)f2bf(v1 - bf2f(h1));
        }
        a0 = __builtin_amdgcn_mfma_f32_16x16x32_bf16(ah, b0h, a0, 0, 0, 0);
        a0 = __builtin_amdgcn_mfma_f32_16x16x32_bf16(al, b0h, a0, 0, 0, 0);
        a0 = __builtin_amdgcn_mfma_f32_16x16x32_bf16(ah, b0l, a0, 0, 0, 0);
        a1 = __builtin_amdgcn_mfma_f32_16x16x32_bf16(ah, b1h, a1, 0, 0, 0);
        a1 = __builtin_amdgcn_mfma_f32_16x16x32_bf16(al, b1h, a1, 0, 0, 0);
        a1 = __builtin_amdgcn_mfma_f32_16x16x32_bf16(ah, b1l, a1, 0, 0, 0);
    }

    // H slice -> LDS (row-agg input) and global (col-phase input)
    #pragma unroll
    for (int i = 0; i < 4; ++i) {
        const int rl = w * 16 + kg * 4 + i;       // 0..127 local node
        sh_h[rl][c]      = a0[i];
        sh_h[rl][16 + c] = a1[i];
        p.H[(size_t)(row0 + kg * 4 + i) * D + col0 + c]      = a0[i];
        p.H[(size_t)(row0 + kg * 4 + i) * D + col0 + 16 + c] = a1[i];
    }

    // attention scalars for head h
    const float as0 = att_s[col0 + c],  as1v = att_s[col0 + 16 + c];
    const float ad0 = att_d[col0 + c],  ad1v = att_d[col0 + 16 + c];
    #pragma unroll
    for (int i = 0; i < 4; ++i) {
        float ps = a0[i] * as0 + a1[i] * as1v;
        float pd = a0[i] * ad0 + a1[i] * ad1v;
        ps += __shfl_xor(ps, 1); pd += __shfl_xor(pd, 1);
        ps += __shfl_xor(ps, 2); pd += __shfl_xor(pd, 2);
        ps += __shfl_xor(ps, 4); pd += __shfl_xor(pd, 4);
        ps += __shfl_xor(ps, 8); pd += __shfl_xor(pd, 8);
        if (c == 0) {
            const int rl = w * 16 + kg * 4 + i;
            sh_as[rl] = ps;
            sh_ad[rl] = pd;
            p.asrc[(row0 + kg * 4 + i) * 4 + h] = ps;
            p.adst[(row0 + kg * 4 + i) * 4 + h] = pd;
        }
    }
    __syncthreads();

    // block-local row aggregation: thread = (dst d, feat-group fg)
    const int d = t >> 2, fg = t & 3;
    const float ad = sh_ad[d];
    f32x4 n0 = {0,0,0,0}, n1 = {0,0,0,0};
    float dn = 0.f;
    #pragma unroll 4
    for (int cp = 0; cp < S_SPAN; ++cp) {
        float e = sh_as[cp] + ad;
        e = fmaxf(e, 0.2f * e);
        float wgt = __expf(e);
        dn += wgt;
        f32x4 h0 = *(f32x4*)&sh_h[cp][fg * 8];
        f32x4 h1 = *(f32x4*)&sh_h[cp][fg * 8 + 4];
        #pragma unroll
        for (int q = 0; q < 4; ++q) {
            n0[q] = fmaf(wgt, h0[q], n0[q]);
            n1[q] = fmaf(wgt, h1[q], n1[q]);
        }
    }
    const int node = r * S_SPAN + d;
    *(f32x4*)&p.numr[(size_t)node * D + col0 + fg * 8]     = n0;
    *(f32x4*)&p.numr[(size_t)node * D + col0 + fg * 8 + 4] = n1;
    if (fg == 0) p.den[node * 4 + h] = dn;
}

// ---------------------------------------------------------------------------
// COL phase: block c (only b < 128 active). Stages H[:,c,:] (48x128), adds
// col-part (excluding own row), merges with row numerators, bias + ELU.
// LAYER==1 -> write split-bf16 x2; LAYER==2 -> write fp32 out.
// ---------------------------------------------------------------------------
template<int LAYER>
__device__ void col_phase(const Params& p, float* sm, int b, int t)
{
    if (b >= S_SPAN) return;
    const int c = b;
    float (*sh_hc)[132] = (float(*)[132])sm;                 // 48 x 132 (pad)
    float (*sh_asc)[T_TRIG] = (float(*)[T_TRIG])(sm + 48 * 132);

    #pragma unroll
    for (int it = 0; it < 3; ++it) {
        int chunk = t + it * BLK;                 // 1536 float4 chunks
        int tt = chunk >> 5, fc = chunk & 31;
        *(float4*)&sh_hc[tt][fc * 4] =
            *(const float4*)&p.H[(size_t)(tt * S_SPAN + c) * D + fc * 4];
    }
    if (t < 4 * T_TRIG) {
        int hh = t / T_TRIG, tt = t - hh * T_TRIG;
        sh_asc[hh][tt] = p.asrc[(tt * S_SPAN + c) * 4 + hh];
    }
    __syncthreads();

    const int f4g = t & 31, tg = t >> 5, head = f4g >> 3;    // tg 0..15, 3 dsts each
    const float* bias = (LAYER == 1) ? p.b1 : p.b2;

    f32x4 num[3] = {{0,0,0,0},{0,0,0,0},{0,0,0,0}};
    float dn[3] = {0.f, 0.f, 0.f};
    float ad[3];
    #pragma unroll
    for (int dd = 0; dd < 3; ++dd)
        ad[dd] = p.adst[((tg * 3 + dd) * S_SPAN + c) * 4 + head];

    for (int tp = 0; tp < T_TRIG; ++tp) {
        float a = sh_asc[head][tp];
        f32x4 hv = *(f32x4*)&sh_hc[tp][f4g * 4];
        #pragma unroll
        for (int dd = 0; dd < 3; ++dd) {
            float e = a + ad[dd];
            e = fmaxf(e, 0.2f * e);
            float wgt = __expf(e);
            wgt = (tp == tg * 3 + dd) ? 0.f : wgt;   // exclude own row
            dn[dd] += wgt;
            #pragma unroll
            for (int q = 0; q < 4; ++q) num[dd][q] = fmaf(wgt, hv[q], num[dd][q]);
        }
    }

    const float4 b4 = *(const float4*)&bias[f4g * 4];
    const float bb[4] = {b4.x, b4.y, b4.z, b4.w};
    #pragma unroll
    for (int dd = 0; dd < 3; ++dd) {
        const int n = (tg * 3 + dd) * S_SPAN + c;
        f32x4 nr = *(const f32x4*)&p.numr[(size_t)n * D + f4g * 4];
        float inv = 1.f / (p.den[n * 4 + head] + dn[dd]);
        float o[4];
        #pragma unroll
        for (int q = 0; q < 4; ++q) {
            o[q] = (nr[q] + num[dd][q]) * inv + bb[q];
            o[q] = o[q] > 0.f ? o[q] : (__expf(o[q]) - 1.f);
        }
        if (LAYER == 1) {
            us4 hv4, lv4;
            #pragma unroll
            for (int q = 0; q < 4; ++q) {
                unsigned short hq = f2bf(o[q]);
                hv4[q] = hq;
                lv4[q] = f2bf(o[q] - bf2f(hq));
            }
            *(us4*)&p.x2h[(size_t)n * D + f4g * 4] = hv4;
            *(us4*)&p.x2l[(size_t)n * D + f4g * 4] = lv4;
        } else {
            float4 o4 = {o[0], o[1], o[2], o[3]};
            *(float4*)&p.out[(size_t)n * D + f4g * 4] = o4;
        }
    }
}

// ---- the single fused kernel: 4 phases, 3 grid barriers --------------------
__global__ __launch_bounds__(BLK, 2) void fused_gat_kernel(Params p)
{
    __shared__ float sm[48 * 132 + 4 * T_TRIG];   // 26.1 KB (col-phase max)
    const int b = blockIdx.x, t = threadIdx.x;

    gr_phase<1>(p, sm, b, t);
    gridbar(p.bar + 0);
    col_phase<1>(p, sm, b, t);
    gridbar(p.bar + 32);
    gr_phase<2>(p, sm, b, t);
    gridbar(p.bar + 64);
    col_phase<2>(p, sm, b, t);
}

// ---------------------------------------------------------------------------
extern "C" void kernel_launch(void* const* d_in, const int* in_sizes, int n_in,
                              void* d_out, int out_size, void* d_ws, size_t ws_size,
                              hipStream_t stream)
{
    Params p;
    p.pe  = (const float*)d_in[0];
    p.W1  = (const float*)d_in[1];
    p.as1 = (const float*)d_in[2];
    p.ad1 = (const float*)d_in[3];
    p.b1  = (const float*)d_in[4];
    p.W2  = (const float*)d_in[5];
    p.as2 = (const float*)d_in[6];
    p.ad2 = (const float*)d_in[7];
    p.b2  = (const float*)d_in[8];
    p.out = (float*)d_out;

    char* ws = (char*)d_ws;
    size_t off = 0;
    auto alloc = [&](size_t bytes) { char* r = ws + off; off += (bytes + 255) & ~255ull; return r; };
    p.bar  = (unsigned int*)alloc(512);
    p.x2h  = (unsigned short*)alloc((size_t)NN * D * 2);
    p.x2l  = (unsigned short*)alloc((size_t)NN * D * 2);
    p.H    = (float*)alloc((size_t)NN * D * 4);
    p.numr = (float*)alloc((size_t)NN * D * 4);
    p.asrc = (float*)alloc((size_t)NN * 4 * 4);
    p.adst = (float*)alloc((size_t)NN * 4 * 4);
    p.den  = (float*)alloc((size_t)NN * 4 * 4);

    hipMemsetAsync(p.bar, 0, 512, stream);
    fused_gat_kernel<<<dim3(GRID), dim3(BLK), 0, stream>>>(p);
}